// Round 31
// baseline (51.656 us; speedup 1.0000x reference)
//
#include <hip/hip_runtime.h>
#include <hip/hip_bf16.h>
#include <stdint.h>

#define VOCAB 50257
#define HID 512
#define LABELS 64
#define KSPLIT 2
#define KLEN 256           // HID / KSPLIT
#define TILEV 64
#define NTILES ((VOCAB + TILEV - 1) / TILEV)   // 786

typedef __attribute__((ext_vector_type(8))) short bf16x8;
typedef __attribute__((ext_vector_type(4))) float f32x4;

__device__ __forceinline__ ushort f2bf(float x) {
    uint32_t u = __float_as_uint(x);
    return (ushort)((u + 0x7fffu + ((u >> 16) & 1u)) >> 16);   // RNE
}

__device__ __forceinline__ float bflo(uint32_t u) {   // low ushort -> float
    return __uint_as_float(u << 16);
}
__device__ __forceinline__ float bfhi(uint32_t u) {   // high ushort -> float
    return __uint_as_float(u & 0xffff0000u);
}

// ---------------------------------------------------------------------------
// K1: P[s][v][l] = sum_{h in split s} w1[h,v]*w2[l,h], bf16 MFMA, KSPLIT=2.
// R30 structure (40.4us: w1 read once, bf16 partials, 4-wave quadrant
// blocks, merged bias) with ONE delta: B loaded DIRECTLY from w2 (128 KB,
// L2-resident) per chunk — NO LDS, NO barrier. LDS was 33.8 KB capping
// blocks at 4/CU (occ 31%, build HBM 1.47/6.3 TB/s = latency-exposed);
// zero LDS lifts the cap to the 2048-thread / VGPR limit (6-8 blocks/CU).
// MFMA/store mapping byte-identical to R28/R29/R30 (hardware-verified).
// ---------------------------------------------------------------------------
#define MFMA_B16(a, b, c) __builtin_amdgcn_mfma_f32_16x16x32_bf16(a, b, c, 0, 0, 0)

#define PACK8(ar, dst)                                                        \
    {                                                                         \
        union { uint32_t u[4]; bf16x8 v; } _x;                                \
        _Pragma("unroll")                                                     \
        for (int j = 0; j < 4; ++j)                                           \
            _x.u[j] = (uint32_t)f2bf(ar[2 * j]) |                             \
                      ((uint32_t)f2bf(ar[2 * j + 1]) << 16);                  \
        dst = _x.v;                                                           \
    }

#define STORE_ONE(accv, m, n)                                                 \
    {                                                                         \
        int vb = v0 + vhalf * 32 + (m) * 16 + kg * 4;                         \
        int l  = lbase + (n) * 16 + lrow;                                     \
        _Pragma("unroll")                                                     \
        for (int rr = 0; rr < 4; ++rr)                                        \
            if (fullA || (vb + rr) < VOCAB)                                   \
                Pout[(size_t)(vb + rr) * LABELS + l] = f2bf(accv[rr]);        \
    }

__global__ __launch_bounds__(256) void build_mfma(
    const float* __restrict__ w1,   // [HID][VOCAB]
    const float* __restrict__ w2,   // [LABELS][HID]
    const float* __restrict__ b1,   // [HID]
    const float* __restrict__ b2,   // [LABELS]
    ushort* __restrict__ P,         // [KSPLIT][VOCAB][LABELS] bf16 partials
    float* __restrict__ C)          // [LABELS] combined bias (fp32, exact)
{
    const int t = threadIdx.x;      // 0..255

    // ---- merged bias block (R23/R29/R30-verified) ----
    if (blockIdx.x == NTILES) {
        if (blockIdx.y == 0 && t < LABELS) {
            float s = b2[t];
            for (int h = 0; h < HID; h += 4) {
                float4 wv4 = *(const float4*)&w2[t * HID + h];
                float4 bv4 = *(const float4*)&b1[h];
                s += wv4.x * bv4.x + wv4.y * bv4.y + wv4.z * bv4.z + wv4.w * bv4.w;
            }
            C[t] = s;
        }
        return;
    }

    const int lane  = t & 63;
    const int wv    = t >> 6;       // wave 0..3
    const int vhalf = wv & 1;       // v-rows vhalf*32..+31
    const int lhalf = wv >> 1;      // labels lhalf*32..+31
    const int lrow  = lane & 15;
    const int kg    = lane >> 4;
    const int v0    = blockIdx.x * TILEV;
    const int hbase = blockIdx.y * KLEN;
    const int lbase = lhalf * 32;
    ushort* Pout = P + (size_t)blockIdx.y * VOCAB * LABELS;
    const bool fullA = (v0 + TILEV <= VOCAB);

    const int vA0 = v0 + vhalf * 32 + lrow;
    const int vA1 = vA0 + 16;
    const bool ok0 = fullA || (vA0 < VOCAB);
    const bool ok1 = fullA || (vA1 < VOCAB);

    // B source rows for this lane (L2-hot w2): labels lbase+lrow, +16
    const float* gB0 = &w2[(lbase + lrow) * HID + hbase + kg * 8];
    const float* gB1 = gB0 + 16 * HID;

    f32x4 acc00 = {0,0,0,0}, acc01 = {0,0,0,0};
    f32x4 acc10 = {0,0,0,0}, acc11 = {0,0,0,0};

#pragma unroll 2
    for (int c = 0; c < KLEN / 32; ++c) {   // 8 chunks
        float ar0[8], ar1[8], br0[8], br1[8];
        {
            const float* g = &w1[(size_t)(hbase + c * 32 + kg * 8) * VOCAB];
#pragma unroll
            for (int j = 0; j < 8; ++j)
                ar0[j] = ok0 ? g[(size_t)j * VOCAB + vA0] : 0.f;
#pragma unroll
            for (int j = 0; j < 8; ++j)
                ar1[j] = ok1 ? g[(size_t)j * VOCAB + vA1] : 0.f;
        }
        *(float4*)&br0[0] = *(const float4*)(gB0 + c * 32);
        *(float4*)&br0[4] = *(const float4*)(gB0 + c * 32 + 4);
        *(float4*)&br1[0] = *(const float4*)(gB1 + c * 32);
        *(float4*)&br1[4] = *(const float4*)(gB1 + c * 32 + 4);
        bf16x8 a0, a1, b0, b1f;
        PACK8(ar0, a0);
        PACK8(ar1, a1);
        PACK8(br0, b0);
        PACK8(br1, b1f);
        acc00 = MFMA_B16(a0, b0, acc00);  acc01 = MFMA_B16(a0, b1f, acc01);
        acc10 = MFMA_B16(a1, b0, acc10);  acc11 = MFMA_B16(a1, b1f, acc11);
    }

    STORE_ONE(acc00, 0, 0); STORE_ONE(acc01, 0, 1);
    STORE_ONE(acc10, 1, 0); STORE_ONE(acc11, 1, 1);
}

// ---------------------------------------------------------------------------
// K2: out[tok][l] = sum_s bf16 P[s][idx[tok]][l] + bias[l]  (R29/R30-verified)
// ---------------------------------------------------------------------------
__global__ __launch_bounds__(256) void gather_out(
    const int* __restrict__ idx,
    const ushort* __restrict__ P,
    const float* __restrict__ bias,
    float* __restrict__ out,
    int ntok)
{
    int g   = blockIdx.x * 256 + threadIdx.x;
    int tok = g >> 4;
    int j   = g & 15;
    if (tok >= ntok) return;
    int v = idx[tok];
    float4 s = ((const float4*)bias)[j];
    const ushort* p0 = P + (size_t)v * LABELS + j * 4;
    const ushort* p1 = p0 + (size_t)VOCAB * LABELS;
    uint2 a = *(const uint2*)p0;
    uint2 b = *(const uint2*)p1;
    s.x += bflo(a.x) + bflo(b.x);
    s.y += bfhi(a.x) + bfhi(b.x);
    s.z += bflo(a.y) + bflo(b.y);
    s.w += bfhi(a.y) + bfhi(b.y);
    ((float4*)out)[(size_t)tok * 16 + j] = s;
}

// ---------------------------------------------------------------------------
// Fallback (ws too small for the tables): direct per-token dot.
// ---------------------------------------------------------------------------
__global__ __launch_bounds__(256) void direct_kernel(
    const int* __restrict__ idx,
    const float* __restrict__ w1,
    const float* __restrict__ b1,
    const float* __restrict__ w2,
    const float* __restrict__ b2,
    float* __restrict__ out,
    int ntok)
{
    int g   = blockIdx.x * 256 + threadIdx.x;
    int tok = g >> 6;
    int l   = g & 63;
    if (tok >= ntok) return;
    int v = idx[tok];
    float acc = b2[l];
    for (int h = 0; h < HID; ++h)
        acc += (w1[(size_t)h * VOCAB + v] + b1[h]) * w2[l * HID + h];
    out[(size_t)tok * 64 + l] = acc;
}

extern "C" void kernel_launch(void* const* d_in, const int* in_sizes, int n_in,
                              void* d_out, int out_size, void* d_ws, size_t ws_size,
                              hipStream_t stream) {
    const int*   idx = (const int*)d_in[0];
    const float* w1  = (const float*)d_in[1];
    const float* b1  = (const float*)d_in[2];
    const float* w2  = (const float*)d_in[3];
    const float* b2  = (const float*)d_in[4];
    float* out = (float*)d_out;
    const int ntok = in_sizes[0];   // 8*4096 = 32768

    const size_t ptab_bytes = (size_t)KSPLIT * VOCAB * LABELS * sizeof(ushort); // ~12.9 MB
    const int nblk2 = (ntok * 16 + 255) / 256;                                  // 2048

    if (ws_size >= ptab_bytes + 1024) {
        // fast path: KSPLIT=2 MFMA build, bf16 partials, zero-LDS direct-B
        ushort* P = (ushort*)d_ws;
        float*  C = (float*)((char*)d_ws + ptab_bytes);
        dim3 grid1(NTILES + 1, KSPLIT);                    // 787 x 2 (last x = bias)
        build_mfma<<<grid1, 256, 0, stream>>>(w1, w2, b1, b2, P, C);
        gather_out<<<nblk2, 256, 0, stream>>>(idx, P, C, out, ntok);
    } else {
        int nblk = (ntok * 64 + 255) / 256;
        direct_kernel<<<nblk, 256, 0, stream>>>(idx, w1, b1, w2, b2, out, ntok);
    }
}

// Round 32
// 40.519 us; speedup vs baseline: 1.2749x; 1.2749x over previous
//
#include <hip/hip_runtime.h>
#include <hip/hip_bf16.h>
#include <stdint.h>

#define VOCAB 50257
#define HID 512
#define LABELS 64
#define KSPLIT 2
#define KLEN 256           // HID / KSPLIT
#define TILEV 64
#define NTILES ((VOCAB + TILEV - 1) / TILEV)   // 786
#define BP 264             // B row pitch in ushorts (256 h + 8 pad) = 528 B

typedef __attribute__((ext_vector_type(8))) short bf16x8;
typedef __attribute__((ext_vector_type(4))) float f32x4;

__device__ __forceinline__ ushort f2bf(float x) {
    uint32_t u = __float_as_uint(x);
    return (ushort)((u + 0x7fffu + ((u >> 16) & 1u)) >> 16);   // RNE
}

__device__ __forceinline__ float bflo(uint32_t u) {   // low ushort -> float
    return __uint_as_float(u << 16);
}
__device__ __forceinline__ float bfhi(uint32_t u) {   // high ushort -> float
    return __uint_as_float(u & 0xffff0000u);
}

__device__ __forceinline__ bf16x8 ld_frag(const ushort* p) {  // p 8B-aligned
    union { uint2 u[2]; bf16x8 v; } x;
    x.u[0] = *(const uint2*)(p);
    x.u[1] = *(const uint2*)(p + 4);
    return x.v;
}

// ---------------------------------------------------------------------------
// K1: P[s][v][l] = sum_{h in split s} w1[h,v]*w2[l,h], bf16 MFMA, KSPLIT=2.
// R30 measured-best (40.4us). w1 read once; bf16 partials; 256-thr/4-wave
// quadrant blocks (vhalf=wv&1 -> 32v, lhalf=wv>>1 -> 32l); B staged in LDS
// (R31 proved direct-B regresses: ds_read ~12cy << L2 ~200cy per chunk);
// merged bias block. MFMA/store mapping hardware-verified 6x.
// ---------------------------------------------------------------------------
#define MFMA_B16(a, b, c) __builtin_amdgcn_mfma_f32_16x16x32_bf16(a, b, c, 0, 0, 0)

#define PACK8(ar, dst)                                                        \
    {                                                                         \
        union { uint32_t u[4]; bf16x8 v; } _x;                                \
        _Pragma("unroll")                                                     \
        for (int j = 0; j < 4; ++j)                                           \
            _x.u[j] = (uint32_t)f2bf(ar[2 * j]) |                             \
                      ((uint32_t)f2bf(ar[2 * j + 1]) << 16);                  \
        dst = _x.v;                                                           \
    }

#define STORE_ONE(accv, m, n)                                                 \
    {                                                                         \
        int vb = v0 + vhalf * 32 + (m) * 16 + kg * 4;                         \
        int l  = lbase + (n) * 16 + lrow;                                     \
        _Pragma("unroll")                                                     \
        for (int rr = 0; rr < 4; ++rr)                                        \
            if (fullA || (vb + rr) < VOCAB)                                   \
                Pout[(size_t)(vb + rr) * LABELS + l] = f2bf(accv[rr]);        \
    }

__global__ __launch_bounds__(256) void build_mfma(
    const float* __restrict__ w1,   // [HID][VOCAB]
    const float* __restrict__ w2,   // [LABELS][HID]
    const float* __restrict__ b1,   // [HID]
    const float* __restrict__ b2,   // [LABELS]
    ushort* __restrict__ P,         // [KSPLIT][VOCAB][LABELS] bf16 partials
    float* __restrict__ C)          // [LABELS] combined bias (fp32, exact)
{
    const int t = threadIdx.x;      // 0..255

    // ---- merged bias block (R23/R29/R30-verified) ----
    if (blockIdx.x == NTILES) {
        if (blockIdx.y == 0 && t < LABELS) {
            float s = b2[t];
            for (int h = 0; h < HID; h += 4) {
                float4 wv4 = *(const float4*)&w2[t * HID + h];
                float4 bv4 = *(const float4*)&b1[h];
                s += wv4.x * bv4.x + wv4.y * bv4.y + wv4.z * bv4.z + wv4.w * bv4.w;
            }
            C[t] = s;
        }
        return;
    }

    __shared__ ushort lB[LABELS * BP];     // [l][h] bf16 w2 K-slice (~33 KB)

    const int lane  = t & 63;
    const int wv    = t >> 6;       // wave 0..3
    const int vhalf = wv & 1;       // v-rows vhalf*32..+31
    const int lhalf = wv >> 1;      // labels lhalf*32..+31
    const int lrow  = lane & 15;
    const int kg    = lane >> 4;
    const int v0    = blockIdx.x * TILEV;
    const int hbase = blockIdx.y * KLEN;
    const int lbase = lhalf * 32;
    ushort* Pout = P + (size_t)blockIdx.y * VOCAB * LABELS;
    const bool fullA = (v0 + TILEV <= VOCAB);

    const int vA0 = v0 + vhalf * 32 + lrow;
    const int vA1 = vA0 + 16;
    const bool ok0 = fullA || (vA0 < VOCAB);
    const bool ok1 = fullA || (vA1 < VOCAB);

    // ---- stage B once: 64l x 256h fp32 -> bf16. 16 float4 per thread.
#pragma unroll
    for (int i = 0; i < 16; ++i) {
        int e  = t + 256 * i;       // 0..4095
        int l  = e >> 6;            // 0..63
        int hq = e & 63;            // float4 index within row
        float4 wv4 = *(const float4*)&w2[l * HID + hbase + hq * 4];
        uint32_t q0 = (uint32_t)f2bf(wv4.x) | ((uint32_t)f2bf(wv4.y) << 16);
        uint32_t q1 = (uint32_t)f2bf(wv4.z) | ((uint32_t)f2bf(wv4.w) << 16);
        *(uint32_t*)&lB[l * BP + hq * 4]     = q0;
        *(uint32_t*)&lB[l * BP + hq * 4 + 2] = q1;
    }
    __syncthreads();                // the only barrier

    f32x4 acc00 = {0,0,0,0}, acc01 = {0,0,0,0};
    f32x4 acc10 = {0,0,0,0}, acc11 = {0,0,0,0};

#pragma unroll 2
    for (int c = 0; c < KLEN / 32; ++c) {   // 8 chunks
        float ar0[8], ar1[8];
        {
            const float* g = &w1[(size_t)(hbase + c * 32 + kg * 8) * VOCAB];
#pragma unroll
            for (int j = 0; j < 8; ++j)
                ar0[j] = ok0 ? g[(size_t)j * VOCAB + vA0] : 0.f;
#pragma unroll
            for (int j = 0; j < 8; ++j)
                ar1[j] = ok1 ? g[(size_t)j * VOCAB + vA1] : 0.f;
        }
        bf16x8 a0, a1;
        PACK8(ar0, a0);
        PACK8(ar1, a1);
        const ushort* bb = &lB[(lbase + lrow) * BP + c * 32 + kg * 8];
        bf16x8 b0  = ld_frag(bb);
        bf16x8 b1f = ld_frag(bb + 16 * BP);
        acc00 = MFMA_B16(a0, b0, acc00);  acc01 = MFMA_B16(a0, b1f, acc01);
        acc10 = MFMA_B16(a1, b0, acc10);  acc11 = MFMA_B16(a1, b1f, acc11);
    }

    STORE_ONE(acc00, 0, 0); STORE_ONE(acc01, 0, 1);
    STORE_ONE(acc10, 1, 0); STORE_ONE(acc11, 1, 1);
}

// ---------------------------------------------------------------------------
// K2: out[tok][l] = sum_s bf16 P[s][idx[tok]][l] + bias[l]  (R29/R30-verified)
// ---------------------------------------------------------------------------
__global__ __launch_bounds__(256) void gather_out(
    const int* __restrict__ idx,
    const ushort* __restrict__ P,
    const float* __restrict__ bias,
    float* __restrict__ out,
    int ntok)
{
    int g   = blockIdx.x * 256 + threadIdx.x;
    int tok = g >> 4;
    int j   = g & 15;
    if (tok >= ntok) return;
    int v = idx[tok];
    float4 s = ((const float4*)bias)[j];
    const ushort* p0 = P + (size_t)v * LABELS + j * 4;
    const ushort* p1 = p0 + (size_t)VOCAB * LABELS;
    uint2 a = *(const uint2*)p0;
    uint2 b = *(const uint2*)p1;
    s.x += bflo(a.x) + bflo(b.x);
    s.y += bfhi(a.x) + bfhi(b.x);
    s.z += bflo(a.y) + bflo(b.y);
    s.w += bfhi(a.y) + bfhi(b.y);
    ((float4*)out)[(size_t)tok * 16 + j] = s;
}

// ---------------------------------------------------------------------------
// Fallback (ws too small for the tables): direct per-token dot.
// ---------------------------------------------------------------------------
__global__ __launch_bounds__(256) void direct_kernel(
    const int* __restrict__ idx,
    const float* __restrict__ w1,
    const float* __restrict__ b1,
    const float* __restrict__ w2,
    const float* __restrict__ b2,
    float* __restrict__ out,
    int ntok)
{
    int g   = blockIdx.x * 256 + threadIdx.x;
    int tok = g >> 6;
    int l   = g & 63;
    if (tok >= ntok) return;
    int v = idx[tok];
    float acc = b2[l];
    for (int h = 0; h < HID; ++h)
        acc += (w1[(size_t)h * VOCAB + v] + b1[h]) * w2[l * HID + h];
    out[(size_t)tok * 64 + l] = acc;
}

extern "C" void kernel_launch(void* const* d_in, const int* in_sizes, int n_in,
                              void* d_out, int out_size, void* d_ws, size_t ws_size,
                              hipStream_t stream) {
    const int*   idx = (const int*)d_in[0];
    const float* w1  = (const float*)d_in[1];
    const float* b1  = (const float*)d_in[2];
    const float* w2  = (const float*)d_in[3];
    const float* b2  = (const float*)d_in[4];
    float* out = (float*)d_out;
    const int ntok = in_sizes[0];   // 8*4096 = 32768

    const size_t ptab_bytes = (size_t)KSPLIT * VOCAB * LABELS * sizeof(ushort); // ~12.9 MB
    const int nblk2 = (ntok * 16 + 255) / 256;                                  // 2048

    if (ws_size >= ptab_bytes + 1024) {
        // fast path: KSPLIT=2 MFMA build, bf16 partials, 4-wave blocks
        ushort* P = (ushort*)d_ws;
        float*  C = (float*)((char*)d_ws + ptab_bytes);
        dim3 grid1(NTILES + 1, KSPLIT);                    // 787 x 2 (last x = bias)
        build_mfma<<<grid1, 256, 0, stream>>>(w1, w2, b1, b2, P, C);
        gather_out<<<nblk2, 256, 0, stream>>>(idx, P, C, out, ntok);
    } else {
        int nblk = (ntok * 64 + 255) / 256;
        direct_kernel<<<nblk, 256, 0, stream>>>(idx, w1, b1, w2, b2, out, ntok);
    }
}

// Round 33
// 40.481 us; speedup vs baseline: 1.2761x; 1.0009x over previous
//
#include <hip/hip_runtime.h>
#include <hip/hip_bf16.h>
#include <stdint.h>

#define VOCAB 50257
#define HID 512
#define LABELS 64
#define KSPLIT 2
#define KLEN 256           // HID / KSPLIT
#define TILEV 64
#define NTILES ((VOCAB + TILEV - 1) / TILEV)   // 786
#define BP 264             // B row pitch in ushorts (256 h + 8 pad) = 528 B

typedef __attribute__((ext_vector_type(8))) short bf16x8;
typedef __attribute__((ext_vector_type(4))) float f32x4;

__device__ __forceinline__ ushort f2bf(float x) {
    uint32_t u = __float_as_uint(x);
    return (ushort)((u + 0x7fffu + ((u >> 16) & 1u)) >> 16);   // RNE
}

__device__ __forceinline__ float bflo(uint32_t u) {   // low ushort -> float
    return __uint_as_float(u << 16);
}
__device__ __forceinline__ float bfhi(uint32_t u) {   // high ushort -> float
    return __uint_as_float(u & 0xffff0000u);
}

__device__ __forceinline__ bf16x8 ld_frag(const ushort* p) {  // p 8B-aligned
    union { uint2 u[2]; bf16x8 v; } x;
    x.u[0] = *(const uint2*)(p);
    x.u[1] = *(const uint2*)(p + 4);
    return x.v;
}

// ---------------------------------------------------------------------------
// K1: P[s][v][l] = sum_{h in split s} w1[h,v]*w2[l,h], bf16 MFMA, KSPLIT=2.
// R30/R32 measured-best structure (40.4/40.5us). ONE delta: chunk loop
// unroll 2 -> 4. Rationale: PACK8 forces a per-chunk vmcnt wait; unroll 4
// lets the scheduler issue 64 independent A-loads per wave before the
// first pack (2x MLP, VGPR ~+32, still ~5 waves/SIMD). Build was
// 1.47 TB/s profiled @30% occ = latency/MLP-exposed.
// Everything else byte-identical (7x hardware-verified mapping).
// ---------------------------------------------------------------------------
#define MFMA_B16(a, b, c) __builtin_amdgcn_mfma_f32_16x16x32_bf16(a, b, c, 0, 0, 0)

#define PACK8(ar, dst)                                                        \
    {                                                                         \
        union { uint32_t u[4]; bf16x8 v; } _x;                                \
        _Pragma("unroll")                                                     \
        for (int j = 0; j < 4; ++j)                                           \
            _x.u[j] = (uint32_t)f2bf(ar[2 * j]) |                             \
                      ((uint32_t)f2bf(ar[2 * j + 1]) << 16);                  \
        dst = _x.v;                                                           \
    }

#define STORE_ONE(accv, m, n)                                                 \
    {                                                                         \
        int vb = v0 + vhalf * 32 + (m) * 16 + kg * 4;                         \
        int l  = lbase + (n) * 16 + lrow;                                     \
        _Pragma("unroll")                                                     \
        for (int rr = 0; rr < 4; ++rr)                                        \
            if (fullA || (vb + rr) < VOCAB)                                   \
                Pout[(size_t)(vb + rr) * LABELS + l] = f2bf(accv[rr]);        \
    }

__global__ __launch_bounds__(256) void build_mfma(
    const float* __restrict__ w1,   // [HID][VOCAB]
    const float* __restrict__ w2,   // [LABELS][HID]
    const float* __restrict__ b1,   // [HID]
    const float* __restrict__ b2,   // [LABELS]
    ushort* __restrict__ P,         // [KSPLIT][VOCAB][LABELS] bf16 partials
    float* __restrict__ C)          // [LABELS] combined bias (fp32, exact)
{
    const int t = threadIdx.x;      // 0..255

    // ---- merged bias block (R23/R29/R30-verified) ----
    if (blockIdx.x == NTILES) {
        if (blockIdx.y == 0 && t < LABELS) {
            float s = b2[t];
            for (int h = 0; h < HID; h += 4) {
                float4 wv4 = *(const float4*)&w2[t * HID + h];
                float4 bv4 = *(const float4*)&b1[h];
                s += wv4.x * bv4.x + wv4.y * bv4.y + wv4.z * bv4.z + wv4.w * bv4.w;
            }
            C[t] = s;
        }
        return;
    }

    __shared__ ushort lB[LABELS * BP];     // [l][h] bf16 w2 K-slice (~33 KB)

    const int lane  = t & 63;
    const int wv    = t >> 6;       // wave 0..3
    const int vhalf = wv & 1;       // v-rows vhalf*32..+31
    const int lhalf = wv >> 1;      // labels lhalf*32..+31
    const int lrow  = lane & 15;
    const int kg    = lane >> 4;
    const int v0    = blockIdx.x * TILEV;
    const int hbase = blockIdx.y * KLEN;
    const int lbase = lhalf * 32;
    ushort* Pout = P + (size_t)blockIdx.y * VOCAB * LABELS;
    const bool fullA = (v0 + TILEV <= VOCAB);

    const int vA0 = v0 + vhalf * 32 + lrow;
    const int vA1 = vA0 + 16;
    const bool ok0 = fullA || (vA0 < VOCAB);
    const bool ok1 = fullA || (vA1 < VOCAB);

    // ---- stage B once: 64l x 256h fp32 -> bf16. 16 float4 per thread.
#pragma unroll
    for (int i = 0; i < 16; ++i) {
        int e  = t + 256 * i;       // 0..4095
        int l  = e >> 6;            // 0..63
        int hq = e & 63;            // float4 index within row
        float4 wv4 = *(const float4*)&w2[l * HID + hbase + hq * 4];
        uint32_t q0 = (uint32_t)f2bf(wv4.x) | ((uint32_t)f2bf(wv4.y) << 16);
        uint32_t q1 = (uint32_t)f2bf(wv4.z) | ((uint32_t)f2bf(wv4.w) << 16);
        *(uint32_t*)&lB[l * BP + hq * 4]     = q0;
        *(uint32_t*)&lB[l * BP + hq * 4 + 2] = q1;
    }
    __syncthreads();                // the only barrier

    f32x4 acc00 = {0,0,0,0}, acc01 = {0,0,0,0};
    f32x4 acc10 = {0,0,0,0}, acc11 = {0,0,0,0};

#pragma unroll 4
    for (int c = 0; c < KLEN / 32; ++c) {   // 8 chunks
        float ar0[8], ar1[8];
        {
            const float* g = &w1[(size_t)(hbase + c * 32 + kg * 8) * VOCAB];
#pragma unroll
            for (int j = 0; j < 8; ++j)
                ar0[j] = ok0 ? g[(size_t)j * VOCAB + vA0] : 0.f;
#pragma unroll
            for (int j = 0; j < 8; ++j)
                ar1[j] = ok1 ? g[(size_t)j * VOCAB + vA1] : 0.f;
        }
        bf16x8 a0, a1;
        PACK8(ar0, a0);
        PACK8(ar1, a1);
        const ushort* bb = &lB[(lbase + lrow) * BP + c * 32 + kg * 8];
        bf16x8 b0  = ld_frag(bb);
        bf16x8 b1f = ld_frag(bb + 16 * BP);
        acc00 = MFMA_B16(a0, b0, acc00);  acc01 = MFMA_B16(a0, b1f, acc01);
        acc10 = MFMA_B16(a1, b0, acc10);  acc11 = MFMA_B16(a1, b1f, acc11);
    }

    STORE_ONE(acc00, 0, 0); STORE_ONE(acc01, 0, 1);
    STORE_ONE(acc10, 1, 0); STORE_ONE(acc11, 1, 1);
}

// ---------------------------------------------------------------------------
// K2: out[tok][l] = sum_s bf16 P[s][idx[tok]][l] + bias[l]  (R29/R30-verified)
// ---------------------------------------------------------------------------
__global__ __launch_bounds__(256) void gather_out(
    const int* __restrict__ idx,
    const ushort* __restrict__ P,
    const float* __restrict__ bias,
    float* __restrict__ out,
    int ntok)
{
    int g   = blockIdx.x * 256 + threadIdx.x;
    int tok = g >> 4;
    int j   = g & 15;
    if (tok >= ntok) return;
    int v = idx[tok];
    float4 s = ((const float4*)bias)[j];
    const ushort* p0 = P + (size_t)v * LABELS + j * 4;
    const ushort* p1 = p0 + (size_t)VOCAB * LABELS;
    uint2 a = *(const uint2*)p0;
    uint2 b = *(const uint2*)p1;
    s.x += bflo(a.x) + bflo(b.x);
    s.y += bfhi(a.x) + bfhi(b.x);
    s.z += bflo(a.y) + bflo(b.y);
    s.w += bfhi(a.y) + bfhi(b.y);
    ((float4*)out)[(size_t)tok * 16 + j] = s;
}

// ---------------------------------------------------------------------------
// Fallback (ws too small for the tables): direct per-token dot.
// ---------------------------------------------------------------------------
__global__ __launch_bounds__(256) void direct_kernel(
    const int* __restrict__ idx,
    const float* __restrict__ w1,
    const float* __restrict__ b1,
    const float* __restrict__ w2,
    const float* __restrict__ b2,
    float* __restrict__ out,
    int ntok)
{
    int g   = blockIdx.x * 256 + threadIdx.x;
    int tok = g >> 6;
    int l   = g & 63;
    if (tok >= ntok) return;
    int v = idx[tok];
    float acc = b2[l];
    for (int h = 0; h < HID; ++h)
        acc += (w1[(size_t)h * VOCAB + v] + b1[h]) * w2[l * HID + h];
    out[(size_t)tok * 64 + l] = acc;
}

extern "C" void kernel_launch(void* const* d_in, const int* in_sizes, int n_in,
                              void* d_out, int out_size, void* d_ws, size_t ws_size,
                              hipStream_t stream) {
    const int*   idx = (const int*)d_in[0];
    const float* w1  = (const float*)d_in[1];
    const float* b1  = (const float*)d_in[2];
    const float* w2  = (const float*)d_in[3];
    const float* b2  = (const float*)d_in[4];
    float* out = (float*)d_out;
    const int ntok = in_sizes[0];   // 8*4096 = 32768

    const size_t ptab_bytes = (size_t)KSPLIT * VOCAB * LABELS * sizeof(ushort); // ~12.9 MB
    const int nblk2 = (ntok * 16 + 255) / 256;                                  // 2048

    if (ws_size >= ptab_bytes + 1024) {
        // fast path: KSPLIT=2 MFMA build, bf16 partials, unroll-4 chunk loop
        ushort* P = (ushort*)d_ws;
        float*  C = (float*)((char*)d_ws + ptab_bytes);
        dim3 grid1(NTILES + 1, KSPLIT);                    // 787 x 2 (last x = bias)
        build_mfma<<<grid1, 256, 0, stream>>>(w1, w2, b1, b2, P, C);
        gather_out<<<nblk2, 256, 0, stream>>>(idx, P, C, out, ntok);
    } else {
        int nblk = (ntok * 64 + 255) / 256;
        direct_kernel<<<nblk, 256, 0, stream>>>(idx, w1, b1, w2, b2, out, ntok);
    }
}